// Round 13
// baseline (165.612 us; speedup 1.0000x reference)
//
#include <hip/hip_runtime.h>

// bpd_cuda: super-BPD boundary angle diff, 512x512. R13: equality-only labels ->
// fixed-slot condensed ids, LDS-only merge.
//  k_local : per 32x32 tile (1024 thr): pf inline, LDS union-find over intra-tile
//            edges, publish depth-1 par, interior c3, per-tile root slots
//            wlist[tile*64+s] + idx[g]=s (LDS counter). Overflow -> flags[0].
//  k_edges : band scan (270 px/tile): DISTINCT cross-tile edges via 256-slot LDS
//            hash, emitted as CONDENSED-ID pairs (idx reads hidden across 256
//            blocks). Hash-capacity spill -> direct global unite + flags[1].
//  k_merge : ONE block, 1024 thr: LDS union-find over <=16K virtual cids; flat
//            iteration (all threads active); no prefix scan / binary search /
//            min-pixel passes — labels are only compared for equality, so any
//            consistent representative works: par[wlist[v]] = wlist[root].
//  k_output: 32x8 px per block; 33x9 label apron in LDS; c3 array or pf^3 band.
// Slow paths (flags set / ntiles>256): pixel-level global UF + full compression —
// correct for any input, never taken for the 512x512 bench.

static constexpr double PI_D = 3.14159265;
#define VCAP 64       // condensed slots per tile (cid = tile*VCAP + slot)
#define NVMAX 16384   // max virtual condensed nodes = 64 KB LDS
#define EPT  256      // deduped edge-pairs per tile
#define MAXT 1024     // max tiles for wcnt/ecnt arrays

__device__ __constant__ int c_DH[8] = {1, 1, 0, -1, -1, -1, 0, 1};
__device__ __constant__ int c_DW[8] = {0, 1, 1, 1, 0, -1, -1, -1};

// fallback scratch: pf,par,c3,idx (4N) + wlist(NVMAX) + wcnt/ecnt + flags + elist
__device__ int g_fb[4 * 262144 + NVMAX + 2 * MAXT + 64 + 2 * EPT * MAXT];

// ---- LDS union-find (atomicMin path-halving; cheap on-CU atomics) ----
__device__ __forceinline__ int uf_find_lds(int x, int* par) {
    while (true) {
        int p = par[x];
        if (p == x) return x;
        int gp = par[p];
        if (gp == p) return p;
        atomicMin(&par[x], gp);
        x = gp;
    }
}
__device__ __forceinline__ void uf_unite_lds(int u, int v, int* par) {
    int ru = uf_find_lds(u, par);
    int rv = uf_find_lds(v, par);
    while (ru != rv) {
        if (ru > rv) { int t2 = ru; ru = rv; rv = t2; }
        int old = atomicMin(&par[rv], ru);
        if (old == rv) break;
        rv = uf_find_lds(old, par);
        ru = uf_find_lds(ru, par);
    }
}

// ---- global union-find (spill/slow paths): read-only walks, RMW only on hooks ----
__device__ __forceinline__ int find_ro(int x, const int* par) {
    int p = par[x];
    while (p != x) { x = p; p = par[x]; }
    return x;
}
__device__ __forceinline__ void uf_unite(int u, int v, int* par) {
    int ru = find_ro(u, par);
    int rv = find_ro(v, par);
    while (ru != rv) {
        if (ru > rv) { int t2 = ru; ru = rv; rv = t2; }
        int old = atomicMin(&par[rv], ru);
        if (old == rv) break;
        rv = find_ro(old, par);
        ru = find_ro(ru, par);
    }
}

// per-pixel parent direction (bit-exact vs the JAX f32 reference)
__device__ __forceinline__ bool parent_dir(const float* __restrict__ ang, float a,
                                           int i, int j, int H, int W, float thr,
                                           int& nhc, int& nwc) {
    const float a8 = (float)(PI_D / 8.0);
    const float a4 = (float)(PI_D / 4.0);
    float posf = rintf((a + a8) / a4);        // jnp.round == round-half-even == rintf
    if (posf >= 8.0f) posf -= 8.0f;
    const int pos = (int)posf;
    const int nh = i + c_DH[pos];
    const int nw = j + c_DW[pos];
    const bool inb = (nh >= 0) & (nh < H) & (nw >= 0) & (nw < W);
    nhc = min(max(nh, 0), H - 1);
    nwc = min(max(nw, 0), W - 1);
    float ad = fabsf(a - ang[nhc * W + nwc]);
    const float twopi = (float)(2.0 * PI_D);
    ad = fminf(ad, twopi - ad);
    return (!inb) || (ad > thr);
}

// one 32x32 tile per block iteration, 1024 threads = 1 px each
__global__ void __launch_bounds__(1024)
k_local(const float* __restrict__ ang,
        const int* __restrict__ hp, const int* __restrict__ wp,
        const int* __restrict__ tap, int N,
        int* __restrict__ pf, int* __restrict__ par, int* __restrict__ c3,
        int* __restrict__ wlist, int* __restrict__ idx, int* __restrict__ wcnt,
        int* __restrict__ flags) {
    const int H = hp[0], W = wp[0];
    const float thr = (float)((double)tap[0] * PI_D / 180.0);
    const int tpr = (W + 31) >> 5;
    const int ntiles = tpr * ((H + 31) >> 5);
    const bool fastOK = (ntiles <= NVMAX / VCAP);   // 512x512 -> 256 tiles: yes
    __shared__ int lpar[1024];
    __shared__ int lpl[1024];    // local parent id; -1 = parent out-of-tile; lp = root
    __shared__ int scnt;
    const int lp = threadIdx.x;
    const int li = lp >> 5, lj = lp & 31;
    for (int tile = blockIdx.x; tile < ntiles; tile += gridDim.x) {
        const int ti0 = (tile / tpr) << 5, tj0 = (tile % tpr) << 5;
        const int i = ti0 + li, j = tj0 + lj;
        const bool inpix = (i < H) && (j < W);
        const int g = i * W + j;
        if (lp == 0) scnt = 0;
        lpar[lp] = lp;
        int lparent = lp;                 // default: treat as root
        if (inpix) {
            int nh, nw;
            const bool root = parent_dir(ang, ang[g], i, j, H, W, thr, nh, nw);
            pf[g] = root ? g : (nh * W + nw);
            if (!root) {
                const int pli = nh - ti0, plj = nw - tj0;
                lparent = (((unsigned)pli < 32u) && ((unsigned)plj < 32u))
                              ? ((pli << 5) + plj) : -1;
            }
        }
        lpl[lp] = lparent;
        __syncthreads();
        if (inpix) {
            if (lparent != lp) {                       // non-root
                if (lparent >= 0) uf_unite_lds(lp, lparent, lpar);
            } else if (i <= H - 2) {                   // root: window edges
                // dh=0: nearest in-tile right root within 3 (transitively complete)
                for (int d = 1; d <= 3; ++d) {
                    if (lj + d > 31 || j + d > W - 1) break;
                    if (lpl[lp + d] == lp + d) { uf_unite_lds(lp, lp + d, lpar); break; }
                }
                // dh in {1,2}: dw in {-3..2} (single enumeration, from top px)
                for (int dh = 1; dh <= 2; ++dh) {
                    const int nh = i + dh;
                    if (nh > H - 2) break;
                    const int nli = li + dh;
                    if (nli >= 32) break;
                    for (int dw = -3; dw <= 2; ++dw) {
                        const int nw = j + dw;
                        if ((unsigned)nw > (unsigned)(W - 2)) continue;
                        const int nlj = lj + dw;
                        if ((unsigned)nlj > 31u) continue;
                        const int nlp = (nli << 5) + nlj;
                        if (lpl[nlp] == nlp) uf_unite_lds(lp, nlp, lpar);
                    }
                }
            }
        }
        __syncthreads();
        if (inpix) {
            const int lr = uf_find_lds(lp, lpar);
            par[g] = (ti0 + (lr >> 5)) * W + (tj0 + (lr & 31));
            if (lr == lp) {                               // tile-local root
                const int s = atomicAdd(&scnt, 1);        // LDS counter
                if (fastOK && s < VCAP) {
                    wlist[tile * VCAP + s] = g;
                    idx[g] = s;
                } else {
                    flags[0] = 1;                         // overflow -> slow path
                }
            }
            // interior px: 3-hop chase stays in-tile (distance <= 3) -> local ids
            if (li >= 3 && li <= 28 && lj >= 3 && lj <= 28) {
                int v = lpl[lp];
                v = lpl[v];
                v = lpl[v];
                c3[g] = (ti0 + (v >> 5)) * W + (tj0 + (v & 31));
            }
        }
        __syncthreads();
        if (lp == 0 && tile < MAXT) wcnt[tile] = scnt;
        __syncthreads();   // protect scnt/LDS re-init on next iteration
    }
}

// band scan: emit DISTINCT cross-tile edges as CONDENSED-ID pairs via LDS hash
__global__ void k_edges(const int* __restrict__ pf,
                        const int* __restrict__ hp, const int* __restrict__ wp,
                        int N, int* par, int* __restrict__ elist, int* __restrict__ ecnt,
                        const int* __restrict__ idx, int* __restrict__ flags) {
    const int H = hp[0], W = wp[0];
    const int tpr = (W + 31) >> 5;
    const int ntiles = tpr * ((H + 31) >> 5);
    const bool slow = (flags[0] != 0) || (ntiles > NVMAX / VCAP);
    const int tidx = threadIdx.x;
    __shared__ unsigned long long htab[256];
    __shared__ int scnt;
    int li = 0, lj = 0;
    if (tidx < 96) {                       // rows {0,30,31}, all 32 cols
        const int r = tidx >> 5;
        li = (r == 0) ? 0 : 29 + r;
        lj = tidx & 31;
    } else if (tidx < 270) {               // rows 1..29, cols {0,1,2,29,30,31}
        const int u = tidx - 96;
        li = 1 + u / 6;
        const int c = u % 6;
        lj = (c < 3) ? c : 26 + c;
    }
    auto cid_of = [&](int px) {            // condensed id of tile-root pixel
        const int pi = px / W, pj = px - pi * W;
        return ((pi >> 5) * tpr + (pj >> 5)) * VCAP + idx[px];
    };
    for (int tile = blockIdx.x; tile < ntiles; tile += gridDim.x) {
        for (int s = tidx; s < 256; s += blockDim.x) htab[s] = ~0ull;
        if (tidx == 0) scnt = 0;
        __syncthreads();
        const int i = ((tile / tpr) << 5) + li;
        const int j = ((tile % tpr) << 5) + lj;
        if (tidx < 270 && i < H && j < W) {
            const int t = i * W + j;
            auto EMIT = [&](int a, int b) {   // a,b: tile-root pixel ids, diff tiles
                if (a == b) return;
                if (slow) { uf_unite(a, b, par); return; }
                const int lo = min(a, b), hi2 = max(a, b);
                const unsigned long long key =
                    ((unsigned long long)lo << 20) | (unsigned)hi2;   // N < 2^20
                unsigned h = (unsigned)((key * 0x9E3779B97F4A7C15ull) >> 52) & 255u;
                bool fresh = true;
                for (int pr = 0; pr < 16; ++pr) {
                    unsigned long long old = atomicCAS(&htab[h], ~0ull, key);
                    if (old == ~0ull) break;                 // inserted (new)
                    if (old == key) { fresh = false; break; }
                    h = (h + 1) & 255u;                      // probe (full: dup ok)
                }
                if (!fresh) return;
                const int s = atomicAdd(&scnt, 1);
                if (s < EPT) {
                    elist[(tile * EPT + s) * 2] = cid_of(lo);
                    elist[(tile * EPT + s) * 2 + 1] = cid_of(hi2);
                } else {
                    flags[1] = 1;                            // spill: absorb in merge
                    uf_unite(lo, hi2, par);                  // monotone hook
                }
            };
            const int p = pf[t];
            if (p != t) {                                    // parent edge if cross-tile
                const int pi = p / W, pj = p - pi * W;
                if (((pi ^ i) | (pj ^ j)) & ~31) EMIT(par[t], par[p]);
            } else if (i <= H - 2) {
                const int pt = par[t];
                int h0 = -1, h1 = -1;
                // dh=0 dedup'd rightward, cross-tile only (lj+d>31)
                for (int d = (lj >= 29 ? 32 - lj : 4); d <= 3; ++d) {
                    if (j + d > W - 1) break;
                    const int n = t + d;
                    if (pf[n] != n) continue;
                    const int pn = par[n];
                    if (pn == pt || pn == h0 || pn == h1) continue;
                    h1 = h0; h0 = pn;
                    EMIT(pt, pn);
                }
                // dh in {1,2}
                for (int dh = 1; dh <= 2; ++dh) {
                    const int nh = i + dh;
                    if (nh > H - 2) break;
                    const bool rowcross = (li + dh) > 31;
                    for (int dw = -3; dw <= 2; ++dw) {
                        const int nw = j + dw;
                        if ((unsigned)nw > (unsigned)(W - 2)) continue;
                        if (!rowcross && ((unsigned)(lj + dw) <= 31u)) continue;
                        const int n = nh * W + nw;
                        if (pf[n] != n) continue;
                        const int pn = par[n];
                        if (pn == pt || pn == h0 || pn == h1) continue;
                        h1 = h0; h0 = pn;
                        EMIT(pt, pn);
                    }
                }
            }
        }
        __syncthreads();
        if (tidx == 0 && tile < MAXT) ecnt[tile] = scnt;   // may exceed EPT; clamped
        __syncthreads();
    }
}

// single block, 1024 thr: LDS union-find over virtual cids; flat loops, no scan
__global__ void __launch_bounds__(1024)
k_merge(const int* __restrict__ wlist, const int* __restrict__ wcnt,
        const int* __restrict__ elist, const int* __restrict__ ecnt,
        const int* __restrict__ flags,
        const int* __restrict__ hp, const int* __restrict__ wp, int N,
        int* par, const int* __restrict__ idx) {
    const int H = hp[0], W = wp[0];
    const int tpr = (W + 31) >> 5;
    const int ntiles = tpr * ((H + 31) >> 5);
    const int tid = threadIdx.x;
    __shared__ int lpar[NVMAX];           // exactly 64 KB
    const bool slow = (flags[0] != 0) || (ntiles > NVMAX / VCAP);
    if (!slow) {
        const int NV = ntiles * VCAP;
        for (int v = tid; v < NV; v += 1024) lpar[v] = v;
        __syncthreads();
        if (flags[1]) {                   // rare: absorb spill hooks
            for (int v = tid; v < NV; v += 1024) {
                const int t = v >> 6, s = v & (VCAP - 1);
                if (s < min(wcnt[t], VCAP)) {
                    const int px = wlist[v];
                    const int q = par[px];
                    if (q != px) {
                        const int qi = q / W, qj = q - qi * W;
                        const int cq = ((qi >> 5) * tpr + (qj >> 5)) * VCAP + idx[q];
                        uf_unite_lds(v, cq, lpar);
                    }
                }
            }
        }
        const int ED = ntiles * EPT;
        for (int v = tid; v < ED; v += 1024) {
            const int t = v >> 8, s = v & (EPT - 1);
            if (s < min(ecnt[t], EPT))
                uf_unite_lds(elist[2 * v], elist[2 * v + 1], lpar);
        }
        __syncthreads();
        for (int v = tid; v < NV; v += 1024) {
            const int t = v >> 6, s = v & (VCAP - 1);
            if (s < min(wcnt[t], VCAP)) {
                const int r = uf_find_lds(v, lpar);
                par[wlist[v]] = wlist[r];   // any consistent representative works
            }
        }
    } else {
        // slow path: full pixel-level compression (monotone, race-safe)
        for (int t = tid; t < N; t += 1024) par[t] = find_ro(t, par);
    }
}

// 32x8 px per block; 33x9 label apron in LDS (each label chain resolved once)
__global__ void __launch_bounds__(256)
k_output(const float* __restrict__ ang,
         const int* __restrict__ par, const int* __restrict__ pf,
         const int* __restrict__ c3,
         const int* __restrict__ hp, const int* __restrict__ wp,
         float* __restrict__ out) {
    const int H = hp[0], W = wp[0];
    const int i0 = blockIdx.y << 3;
    const int j0 = blockIdx.x << 5;
    __shared__ int lab[9][33];
    const int tid = threadIdx.x;
    for (int k = tid; k < 9 * 33; k += 256) {
        const int r = k / 33, c = k - r * 33;
        const int gi = min(i0 + r, H - 1), gj = min(j0 + c, W - 1);
        lab[r][c] = par[par[gi * W + gj]];
    }
    __syncthreads();
    const int li2 = tid >> 5, lj2 = tid & 31;
    const int i = i0 + li2, j = j0 + lj2;
    if (i >= H || j >= W) return;
    const int t = i * W + j;
    const float twopi = (float)(2.0 * PI_D);
    const int l = lab[li2][lj2];
    float r0 = 0.0f, r1 = 0.0f;
    bool need = false;
    int l1 = l, l2 = l;
    if (j + 1 < W) { l1 = lab[li2][lj2 + 1]; need |= (l1 != l); }
    if (i + 1 < H) { l2 = lab[li2 + 1][lj2]; need |= (l2 != l); }
    if (need) {
        auto c3v = [&](int x, int xli, int xlj) {   // xli/xlj: 32-tile local coords
            if (xli >= 3 && xli <= 28 && xlj >= 3 && xlj <= 28) return c3[x];
            int p = pf[x];
            p = pf[p];
            return pf[p];
        };
        const float ac = ang[c3v(t, i & 31, j & 31)];
        if (l1 != l) {
            float ad = fabsf(ac - ang[c3v(t + 1, i & 31, (j + 1) & 31)]);
            r0 = fminf(ad, twopi - ad);
        }
        if (l2 != l) {
            float ad = fabsf(ac - ang[c3v(t + W, (i + 1) & 31, j & 31)]);
            r1 = fminf(ad, twopi - ad);
        }
    }
    reinterpret_cast<float2*>(out)[t] = make_float2(r0, r1);
}

extern "C" void kernel_launch(void* const* d_in, const int* in_sizes, int n_in,
                              void* d_out, int out_size, void* d_ws, size_t ws_size,
                              hipStream_t stream) {
    const float* ang = (const float*)d_in[0];
    const int* hp  = (const int*)d_in[1];
    const int* wp  = (const int*)d_in[2];
    const int* tap = (const int*)d_in[3];
    const int N = in_sizes[0];

    const size_t need = ((size_t)4 * N + NVMAX + 2 * MAXT + 64
                         + 2 * (size_t)EPT * MAXT) * sizeof(int);
    int* base = (int*)d_ws;
    if (ws_size < need && N <= 262144) {
        void* p = nullptr;
        hipGetSymbolAddress(&p, HIP_SYMBOL(g_fb));   // host-side query; capture-safe
        base = (int*)p;
    }
    int* pf    = base;
    int* par   = base + N;
    int* c3    = base + 2 * N;
    int* idx   = base + 3 * N;
    int* wlist = base + 4 * N;                       // NVMAX (tile*VCAP + slot)
    int* wcnt  = base + 4 * N + NVMAX;               // MAXT
    int* ecnt  = wcnt + MAXT;                        // MAXT
    int* flags = ecnt + MAXT;                        // [0]=overflow, [1]=spill
    int* elist = flags + 64;                         // 2*EPT*MAXT

    hipMemsetAsync(flags, 0, 2 * sizeof(int), stream);

    // Grid shapes assume 512x512 (harness-fixed); kernels bounds-check vs hp/wp.
    k_local <<<256, 1024, 0, stream>>>(ang, hp, wp, tap, N, pf, par, c3,
                                       wlist, idx, wcnt, flags);
    k_edges <<<256, 320, 0, stream>>>(pf, hp, wp, N, par, elist, ecnt, idx, flags);
    k_merge <<<1, 1024, 0, stream>>>(wlist, wcnt, elist, ecnt, flags, hp, wp, N,
                                     par, idx);
    {
        const int H = 512, W = 512;
        dim3 gridO((W + 31) / 32, (H + 7) / 8);
        k_output<<<gridO, 256, 0, stream>>>(ang, par, pf, c3, hp, wp, (float*)d_out);
    }
}

// Round 14
// 101.852 us; speedup vs baseline: 1.6260x; 1.6260x over previous
//
#include <hip/hip_runtime.h>

// bpd_cuda: super-BPD boundary angle diff, 512x512. R14: no single-block phase.
//  k_local    : per 32x32 tile (1024 thr): pf inline, LDS union-find over intra-tile
//               edges, publish depth-1 par, interior c3 via local-id chase.
//  k_edges    : band scan (270 px/tile): cross-tile edges deduped via 256-slot LDS
//               hash; fresh pairs -> DIRECT global uf_unite on par (monotone
//               atomicMin hooks, ~8K unions spread over 256 blocks).
//  k_compress : par[t] = find_ro(t) for ALL pixels (1024 blocks) -> par IS the label.
//  k_output   : 32x8 px per block; 33x9 label apron (single par load per cell);
//               c3 from array (interior) or pf^3 chase (band).
// Labels are only compared for equality downstream, so any consistent component
// representative works (no min-label machinery needed).
// All par mutations: atomicMin hooks (monotone) or final-value plain stores.

static constexpr double PI_D = 3.14159265;

__device__ __constant__ int c_DH[8] = {1, 1, 0, -1, -1, -1, 0, 1};
__device__ __constant__ int c_DW[8] = {0, 1, 1, 1, 0, -1, -1, -1};

// fallback scratch: pf, par, c3 (3N) for N<=262144
__device__ int g_fb[3 * 262144];

// ---- LDS union-find (atomicMin path-halving; cheap on-CU atomics) ----
__device__ __forceinline__ int uf_find_lds(int x, int* par) {
    while (true) {
        int p = par[x];
        if (p == x) return x;
        int gp = par[p];
        if (gp == p) return p;
        atomicMin(&par[x], gp);
        x = gp;
    }
}
__device__ __forceinline__ void uf_unite_lds(int u, int v, int* par) {
    int ru = uf_find_lds(u, par);
    int rv = uf_find_lds(v, par);
    while (ru != rv) {
        if (ru > rv) { int t2 = ru; ru = rv; rv = t2; }
        int old = atomicMin(&par[rv], ru);
        if (old == rv) break;
        rv = uf_find_lds(old, par);
        ru = uf_find_lds(ru, par);
    }
}

// ---- global union-find: read-only walks, RMW only on hooks (ECL-CC style) ----
__device__ __forceinline__ int find_ro(int x, const int* par) {
    int p = par[x];
    while (p != x) { x = p; p = par[x]; }
    return x;
}
__device__ __forceinline__ void uf_unite(int u, int v, int* par) {
    int ru = find_ro(u, par);
    int rv = find_ro(v, par);
    while (ru != rv) {
        if (ru > rv) { int t2 = ru; ru = rv; rv = t2; }
        int old = atomicMin(&par[rv], ru);
        if (old == rv) break;          // rv really was a root: linked
        rv = find_ro(old, par);        // rv was already hooked; merge that comp too
        ru = find_ro(ru, par);
    }
}

// per-pixel parent direction (bit-exact vs the JAX f32 reference)
__device__ __forceinline__ bool parent_dir(const float* __restrict__ ang, float a,
                                           int i, int j, int H, int W, float thr,
                                           int& nhc, int& nwc) {
    const float a8 = (float)(PI_D / 8.0);
    const float a4 = (float)(PI_D / 4.0);
    float posf = rintf((a + a8) / a4);        // jnp.round == round-half-even == rintf
    if (posf >= 8.0f) posf -= 8.0f;
    const int pos = (int)posf;
    const int nh = i + c_DH[pos];
    const int nw = j + c_DW[pos];
    const bool inb = (nh >= 0) & (nh < H) & (nw >= 0) & (nw < W);
    nhc = min(max(nh, 0), H - 1);
    nwc = min(max(nw, 0), W - 1);
    float ad = fabsf(a - ang[nhc * W + nwc]);
    const float twopi = (float)(2.0 * PI_D);
    ad = fminf(ad, twopi - ad);
    return (!inb) || (ad > thr);
}

// one 32x32 tile per block iteration, 1024 threads = 1 px each
__global__ void __launch_bounds__(1024)
k_local(const float* __restrict__ ang,
        const int* __restrict__ hp, const int* __restrict__ wp,
        const int* __restrict__ tap, int N,
        int* __restrict__ pf, int* __restrict__ par, int* __restrict__ c3) {
    const int H = hp[0], W = wp[0];
    const float thr = (float)((double)tap[0] * PI_D / 180.0);
    const int tpr = (W + 31) >> 5;
    const int ntiles = tpr * ((H + 31) >> 5);
    __shared__ int lpar[1024];
    __shared__ int lpl[1024];    // local parent id; -1 = parent out-of-tile; lp = root
    const int lp = threadIdx.x;
    const int li = lp >> 5, lj = lp & 31;
    for (int tile = blockIdx.x; tile < ntiles; tile += gridDim.x) {
        const int ti0 = (tile / tpr) << 5, tj0 = (tile % tpr) << 5;
        const int i = ti0 + li, j = tj0 + lj;
        const bool inpix = (i < H) && (j < W);
        const int g = i * W + j;
        lpar[lp] = lp;
        int lparent = lp;                 // default: treat as root
        if (inpix) {
            int nh, nw;
            const bool root = parent_dir(ang, ang[g], i, j, H, W, thr, nh, nw);
            pf[g] = root ? g : (nh * W + nw);
            if (!root) {
                const int pli = nh - ti0, plj = nw - tj0;
                lparent = (((unsigned)pli < 32u) && ((unsigned)plj < 32u))
                              ? ((pli << 5) + plj) : -1;
            }
        }
        lpl[lp] = lparent;
        __syncthreads();
        if (inpix) {
            if (lparent != lp) {                       // non-root
                if (lparent >= 0) uf_unite_lds(lp, lparent, lpar);
            } else if (i <= H - 2) {                   // root: window edges
                // dh=0: nearest in-tile right root within 3 (transitively complete)
                for (int d = 1; d <= 3; ++d) {
                    if (lj + d > 31 || j + d > W - 1) break;
                    if (lpl[lp + d] == lp + d) { uf_unite_lds(lp, lp + d, lpar); break; }
                }
                // dh in {1,2}: dw in {-3..2} (single enumeration, from top px)
                for (int dh = 1; dh <= 2; ++dh) {
                    const int nh = i + dh;
                    if (nh > H - 2) break;
                    const int nli = li + dh;
                    if (nli >= 32) break;
                    for (int dw = -3; dw <= 2; ++dw) {
                        const int nw = j + dw;
                        if ((unsigned)nw > (unsigned)(W - 2)) continue;
                        const int nlj = lj + dw;
                        if ((unsigned)nlj > 31u) continue;
                        const int nlp = (nli << 5) + nlj;
                        if (lpl[nlp] == nlp) uf_unite_lds(lp, nlp, lpar);
                    }
                }
            }
        }
        __syncthreads();
        if (inpix) {
            const int lr = uf_find_lds(lp, lpar);
            par[g] = (ti0 + (lr >> 5)) * W + (tj0 + (lr & 31));
            // interior px: 3-hop chase stays in-tile (distance <= 3) -> local ids
            if (li >= 3 && li <= 28 && lj >= 3 && lj <= 28) {
                int v = lpl[lp];
                v = lpl[v];
                v = lpl[v];
                c3[g] = (ti0 + (v >> 5)) * W + (tj0 + (v & 31));
            }
        }
        __syncthreads();   // protect LDS re-init on next iteration
    }
}

// band scan: dedup cross-tile edges via LDS hash; fresh pairs -> direct global unite
__global__ void k_edges(const int* __restrict__ pf,
                        const int* __restrict__ hp, const int* __restrict__ wp,
                        int N, int* par) {
    const int H = hp[0], W = wp[0];
    const int tpr = (W + 31) >> 5;
    const int ntiles = tpr * ((H + 31) >> 5);
    const int tidx = threadIdx.x;
    __shared__ unsigned long long htab[256];
    int li = 0, lj = 0;
    if (tidx < 96) {                       // rows {0,30,31}, all 32 cols
        const int r = tidx >> 5;
        li = (r == 0) ? 0 : 29 + r;
        lj = tidx & 31;
    } else if (tidx < 270) {               // rows 1..29, cols {0,1,2,29,30,31}
        const int u = tidx - 96;
        li = 1 + u / 6;
        const int c = u % 6;
        lj = (c < 3) ? c : 26 + c;
    }
    for (int tile = blockIdx.x; tile < ntiles; tile += gridDim.x) {
        for (int s = tidx; s < 256; s += blockDim.x) htab[s] = ~0ull;
        __syncthreads();
        const int i = ((tile / tpr) << 5) + li;
        const int j = ((tile % tpr) << 5) + lj;
        if (tidx < 270 && i < H && j < W) {
            const int t = i * W + j;
            auto EMIT = [&](int a, int b) {   // a,b: tile-root pixel ids, diff tiles
                if (a == b) return;
                const int lo = min(a, b), hi2 = max(a, b);
                const unsigned long long key =
                    ((unsigned long long)lo << 20) | (unsigned)hi2;   // N < 2^20
                unsigned h = (unsigned)((key * 0x9E3779B97F4A7C15ull) >> 52) & 255u;
                bool fresh = true;
                for (int pr = 0; pr < 16; ++pr) {
                    unsigned long long old = atomicCAS(&htab[h], ~0ull, key);
                    if (old == ~0ull) break;                 // inserted (new)
                    if (old == key) { fresh = false; break; }
                    h = (h + 1) & 255u;                      // probe (full: dup ok)
                }
                if (fresh) uf_unite(lo, hi2, par);           // monotone hook
            };
            const int p = pf[t];
            if (p != t) {                                    // parent edge if cross-tile
                const int pi = p / W, pj = p - pi * W;
                if (((pi ^ i) | (pj ^ j)) & ~31) EMIT(par[t], par[p]);
            } else if (i <= H - 2) {
                const int pt = par[t];
                int h0 = -1, h1 = -1;
                // dh=0 dedup'd rightward, cross-tile only (lj+d>31)
                for (int d = (lj >= 29 ? 32 - lj : 4); d <= 3; ++d) {
                    if (j + d > W - 1) break;
                    const int n = t + d;
                    if (pf[n] != n) continue;
                    const int pn = par[n];
                    if (pn == pt || pn == h0 || pn == h1) continue;
                    h1 = h0; h0 = pn;
                    EMIT(pt, pn);
                }
                // dh in {1,2}
                for (int dh = 1; dh <= 2; ++dh) {
                    const int nh = i + dh;
                    if (nh > H - 2) break;
                    const bool rowcross = (li + dh) > 31;
                    for (int dw = -3; dw <= 2; ++dw) {
                        const int nw = j + dw;
                        if ((unsigned)nw > (unsigned)(W - 2)) continue;
                        if (!rowcross && ((unsigned)(lj + dw) <= 31u)) continue;
                        const int n = nh * W + nw;
                        if (pf[n] != n) continue;
                        const int pn = par[n];
                        if (pn == pt || pn == h0 || pn == h1) continue;
                        h1 = h0; h0 = pn;
                        EMIT(pt, pn);
                    }
                }
            }
        }
        __syncthreads();   // protect htab re-init on next iteration
    }
}

// full compression: par[t] <- final component representative (plain store; all
// unions complete at this kernel boundary; concurrent walks read ancestors only)
__global__ void k_compress(int N, int* par) {
    const int t = blockIdx.x * blockDim.x + threadIdx.x;
    if (t >= N) return;
    par[t] = find_ro(t, par);
}

// 32x8 px per block; 33x9 label apron in LDS (single par load per cell)
__global__ void __launch_bounds__(256)
k_output(const float* __restrict__ ang,
         const int* __restrict__ par, const int* __restrict__ pf,
         const int* __restrict__ c3,
         const int* __restrict__ hp, const int* __restrict__ wp,
         float* __restrict__ out) {
    const int H = hp[0], W = wp[0];
    const int i0 = blockIdx.y << 3;
    const int j0 = blockIdx.x << 5;
    __shared__ int lab[9][33];
    const int tid = threadIdx.x;
    for (int k = tid; k < 9 * 33; k += 256) {
        const int r = k / 33, c = k - r * 33;
        const int gi = min(i0 + r, H - 1), gj = min(j0 + c, W - 1);
        lab[r][c] = par[gi * W + gj];          // par is fully compressed
    }
    __syncthreads();
    const int li2 = tid >> 5, lj2 = tid & 31;
    const int i = i0 + li2, j = j0 + lj2;
    if (i >= H || j >= W) return;
    const int t = i * W + j;
    const float twopi = (float)(2.0 * PI_D);
    const int l = lab[li2][lj2];
    float r0 = 0.0f, r1 = 0.0f;
    bool need = false;
    int l1 = l, l2 = l;
    if (j + 1 < W) { l1 = lab[li2][lj2 + 1]; need |= (l1 != l); }
    if (i + 1 < H) { l2 = lab[li2 + 1][lj2]; need |= (l2 != l); }
    if (need) {
        auto c3v = [&](int x, int xli, int xlj) {   // xli/xlj: 32-tile local coords
            if (xli >= 3 && xli <= 28 && xlj >= 3 && xlj <= 28) return c3[x];
            int p = pf[x];
            p = pf[p];
            return pf[p];
        };
        const float ac = ang[c3v(t, i & 31, j & 31)];
        if (l1 != l) {
            float ad = fabsf(ac - ang[c3v(t + 1, i & 31, (j + 1) & 31)]);
            r0 = fminf(ad, twopi - ad);
        }
        if (l2 != l) {
            float ad = fabsf(ac - ang[c3v(t + W, (i + 1) & 31, j & 31)]);
            r1 = fminf(ad, twopi - ad);
        }
    }
    reinterpret_cast<float2*>(out)[t] = make_float2(r0, r1);
}

extern "C" void kernel_launch(void* const* d_in, const int* in_sizes, int n_in,
                              void* d_out, int out_size, void* d_ws, size_t ws_size,
                              hipStream_t stream) {
    const float* ang = (const float*)d_in[0];
    const int* hp  = (const int*)d_in[1];
    const int* wp  = (const int*)d_in[2];
    const int* tap = (const int*)d_in[3];
    const int N = in_sizes[0];

    int* base = (int*)d_ws;
    if (ws_size < (size_t)3 * (size_t)N * sizeof(int) && N <= 262144) {
        void* p = nullptr;
        hipGetSymbolAddress(&p, HIP_SYMBOL(g_fb));   // host-side query; capture-safe
        base = (int*)p;
    }
    int* pf  = base;
    int* par = base + N;
    int* c3  = base + 2 * N;

    // Grid shapes assume 512x512 (harness-fixed); kernels bounds-check vs hp/wp.
    k_local   <<<256, 1024, 0, stream>>>(ang, hp, wp, tap, N, pf, par, c3);
    k_edges   <<<256, 320, 0, stream>>>(pf, hp, wp, N, par);
    k_compress<<<(N + 255) / 256, 256, 0, stream>>>(N, par);
    {
        const int H = 512, W = 512;
        dim3 gridO((W + 31) / 32, (H + 7) / 8);
        k_output<<<gridO, 256, 0, stream>>>(ang, par, pf, c3, hp, wp, (float*)d_out);
    }
}

// Round 15
// 97.194 us; speedup vs baseline: 1.7039x; 1.0479x over previous
//
#include <hip/hip_runtime.h>

// bpd_cuda: super-BPD boundary angle diff, 512x512. R15: 3 dispatches.
//  k_local  : per 32x32 tile (1024 thr): pf inline, LDS union-find over intra-tile
//             edges. Window rows dh in {1,2}: unite with ONLY leftmost+rightmost
//             in-tile root of the 6-wide segment (proof: roots in width-6 span form
//             <=2 gap>3-separated clusters; intra-cluster pairs are chained by that
//             row's dh=0 nearest-right-root unions). Publish depth-1 par; interior
//             c3 via local-id chase.
//  k_edges  : band scan (270 px/tile): cross-tile edges deduped via 256-slot LDS
//             hash; fresh pairs -> direct global uf_unite (monotone atomicMin hooks).
//  k_output : 32x8 px per block; 33x9 label apron via find_ro WALKS (compression
//             fused here — each pixel's label is resolved exactly once per apron);
//             c3 from array (interior) or pf^3 chase (band).
// Labels are only compared for equality, so any consistent representative works.
// All par mutations: atomicMin hooks (monotone) or final-value plain stores.

static constexpr double PI_D = 3.14159265;

__device__ __constant__ int c_DH[8] = {1, 1, 0, -1, -1, -1, 0, 1};
__device__ __constant__ int c_DW[8] = {0, 1, 1, 1, 0, -1, -1, -1};

// fallback scratch: pf, par, c3 (3N) for N<=262144
__device__ int g_fb[3 * 262144];

// ---- LDS union-find (atomicMin path-halving; cheap on-CU atomics) ----
__device__ __forceinline__ int uf_find_lds(int x, int* par) {
    while (true) {
        int p = par[x];
        if (p == x) return x;
        int gp = par[p];
        if (gp == p) return p;
        atomicMin(&par[x], gp);
        x = gp;
    }
}
__device__ __forceinline__ void uf_unite_lds(int u, int v, int* par) {
    int ru = uf_find_lds(u, par);
    int rv = uf_find_lds(v, par);
    while (ru != rv) {
        if (ru > rv) { int t2 = ru; ru = rv; rv = t2; }
        int old = atomicMin(&par[rv], ru);
        if (old == rv) break;
        rv = uf_find_lds(old, par);
        ru = uf_find_lds(ru, par);
    }
}

// ---- global union-find: read-only walks, RMW only on hooks (ECL-CC style) ----
__device__ __forceinline__ int find_ro(int x, const int* par) {
    int p = par[x];
    while (p != x) { x = p; p = par[x]; }
    return x;
}
__device__ __forceinline__ void uf_unite(int u, int v, int* par) {
    int ru = find_ro(u, par);
    int rv = find_ro(v, par);
    while (ru != rv) {
        if (ru > rv) { int t2 = ru; ru = rv; rv = t2; }
        int old = atomicMin(&par[rv], ru);
        if (old == rv) break;          // rv really was a root: linked
        rv = find_ro(old, par);        // rv was already hooked; merge that comp too
        ru = find_ro(ru, par);
    }
}

// per-pixel parent direction (bit-exact vs the JAX f32 reference)
__device__ __forceinline__ bool parent_dir(const float* __restrict__ ang, float a,
                                           int i, int j, int H, int W, float thr,
                                           int& nhc, int& nwc) {
    const float a8 = (float)(PI_D / 8.0);
    const float a4 = (float)(PI_D / 4.0);
    float posf = rintf((a + a8) / a4);        // jnp.round == round-half-even == rintf
    if (posf >= 8.0f) posf -= 8.0f;
    const int pos = (int)posf;
    const int nh = i + c_DH[pos];
    const int nw = j + c_DW[pos];
    const bool inb = (nh >= 0) & (nh < H) & (nw >= 0) & (nw < W);
    nhc = min(max(nh, 0), H - 1);
    nwc = min(max(nw, 0), W - 1);
    float ad = fabsf(a - ang[nhc * W + nwc]);
    const float twopi = (float)(2.0 * PI_D);
    ad = fminf(ad, twopi - ad);
    return (!inb) || (ad > thr);
}

// one 32x32 tile per block iteration, 1024 threads = 1 px each
__global__ void __launch_bounds__(1024)
k_local(const float* __restrict__ ang,
        const int* __restrict__ hp, const int* __restrict__ wp,
        const int* __restrict__ tap, int N,
        int* __restrict__ pf, int* __restrict__ par, int* __restrict__ c3) {
    const int H = hp[0], W = wp[0];
    const float thr = (float)((double)tap[0] * PI_D / 180.0);
    const int tpr = (W + 31) >> 5;
    const int ntiles = tpr * ((H + 31) >> 5);
    __shared__ int lpar[1024];
    __shared__ int lpl[1024];    // local parent id; -1 = parent out-of-tile; lp = root
    const int lp = threadIdx.x;
    const int li = lp >> 5, lj = lp & 31;
    for (int tile = blockIdx.x; tile < ntiles; tile += gridDim.x) {
        const int ti0 = (tile / tpr) << 5, tj0 = (tile % tpr) << 5;
        const int i = ti0 + li, j = tj0 + lj;
        const bool inpix = (i < H) && (j < W);
        const int g = i * W + j;
        lpar[lp] = lp;
        int lparent = lp;                 // default: treat as root
        if (inpix) {
            int nh, nw;
            const bool root = parent_dir(ang, ang[g], i, j, H, W, thr, nh, nw);
            pf[g] = root ? g : (nh * W + nw);
            if (!root) {
                const int pli = nh - ti0, plj = nw - tj0;
                lparent = (((unsigned)pli < 32u) && ((unsigned)plj < 32u))
                              ? ((pli << 5) + plj) : -1;
            }
        }
        lpl[lp] = lparent;
        __syncthreads();
        if (inpix) {
            if (lparent != lp) {                       // non-root
                if (lparent >= 0) uf_unite_lds(lp, lparent, lpar);
            } else if (i <= H - 2) {                   // root: window edges
                // dh=0: nearest in-tile right root within 3 (transitively complete)
                for (int d = 1; d <= 3; ++d) {
                    if (lj + d > 31 || j + d > W - 1) break;
                    if (lpl[lp + d] == lp + d) { uf_unite_lds(lp, lp + d, lpar); break; }
                }
                // dh in {1,2}: unite with leftmost + rightmost in-tile root of the
                // 6-wide segment (intra-cluster pairs covered by that row's dh=0)
                for (int dh = 1; dh <= 2; ++dh) {
                    const int nh = i + dh;
                    if (nh > H - 2) break;
                    const int nli = li + dh;
                    if (nli >= 32) break;
                    int first = -1, last = -1;
                    for (int dw = -3; dw <= 2; ++dw) {
                        const int nw = j + dw;
                        if ((unsigned)nw > (unsigned)(W - 2)) continue;
                        const int nlj = lj + dw;
                        if ((unsigned)nlj > 31u) continue;
                        const int nlp = (nli << 5) + nlj;
                        if (lpl[nlp] == nlp) { if (first < 0) first = nlp; last = nlp; }
                    }
                    if (first >= 0) {
                        uf_unite_lds(lp, first, lpar);
                        if (last != first) uf_unite_lds(lp, last, lpar);
                    }
                }
            }
        }
        __syncthreads();
        if (inpix) {
            const int lr = uf_find_lds(lp, lpar);
            par[g] = (ti0 + (lr >> 5)) * W + (tj0 + (lr & 31));
            // interior px: 3-hop chase stays in-tile (distance <= 3) -> local ids
            if (li >= 3 && li <= 28 && lj >= 3 && lj <= 28) {
                int v = lpl[lp];
                v = lpl[v];
                v = lpl[v];
                c3[g] = (ti0 + (v >> 5)) * W + (tj0 + (v & 31));
            }
        }
        __syncthreads();   // protect LDS re-init on next iteration
    }
}

// band scan: dedup cross-tile edges via LDS hash; fresh pairs -> direct global unite
__global__ void k_edges(const int* __restrict__ pf,
                        const int* __restrict__ hp, const int* __restrict__ wp,
                        int N, int* par) {
    const int H = hp[0], W = wp[0];
    const int tpr = (W + 31) >> 5;
    const int ntiles = tpr * ((H + 31) >> 5);
    const int tidx = threadIdx.x;
    __shared__ unsigned long long htab[256];
    int li = 0, lj = 0;
    if (tidx < 96) {                       // rows {0,30,31}, all 32 cols
        const int r = tidx >> 5;
        li = (r == 0) ? 0 : 29 + r;
        lj = tidx & 31;
    } else if (tidx < 270) {               // rows 1..29, cols {0,1,2,29,30,31}
        const int u = tidx - 96;
        li = 1 + u / 6;
        const int c = u % 6;
        lj = (c < 3) ? c : 26 + c;
    }
    for (int tile = blockIdx.x; tile < ntiles; tile += gridDim.x) {
        for (int s = tidx; s < 256; s += blockDim.x) htab[s] = ~0ull;
        __syncthreads();
        const int i = ((tile / tpr) << 5) + li;
        const int j = ((tile % tpr) << 5) + lj;
        if (tidx < 270 && i < H && j < W) {
            const int t = i * W + j;
            auto EMIT = [&](int a, int b) {   // a,b: tile-root pixel ids, diff tiles
                if (a == b) return;
                const int lo = min(a, b), hi2 = max(a, b);
                const unsigned long long key =
                    ((unsigned long long)lo << 20) | (unsigned)hi2;   // N < 2^20
                unsigned h = (unsigned)((key * 0x9E3779B97F4A7C15ull) >> 52) & 255u;
                bool fresh = true;
                for (int pr = 0; pr < 16; ++pr) {
                    unsigned long long old = atomicCAS(&htab[h], ~0ull, key);
                    if (old == ~0ull) break;                 // inserted (new)
                    if (old == key) { fresh = false; break; }
                    h = (h + 1) & 255u;                      // probe (full: dup ok)
                }
                if (fresh) uf_unite(lo, hi2, par);           // monotone hook
            };
            const int p = pf[t];
            if (p != t) {                                    // parent edge if cross-tile
                const int pi = p / W, pj = p - pi * W;
                if (((pi ^ i) | (pj ^ j)) & ~31) EMIT(par[t], par[p]);
            } else if (i <= H - 2) {
                const int pt = par[t];
                int h0 = -1, h1 = -1;
                // dh=0 dedup'd rightward, cross-tile only (lj+d>31)
                for (int d = (lj >= 29 ? 32 - lj : 4); d <= 3; ++d) {
                    if (j + d > W - 1) break;
                    const int n = t + d;
                    if (pf[n] != n) continue;
                    const int pn = par[n];
                    if (pn == pt || pn == h0 || pn == h1) continue;
                    h1 = h0; h0 = pn;
                    EMIT(pt, pn);
                }
                // dh in {1,2}
                for (int dh = 1; dh <= 2; ++dh) {
                    const int nh = i + dh;
                    if (nh > H - 2) break;
                    const bool rowcross = (li + dh) > 31;
                    for (int dw = -3; dw <= 2; ++dw) {
                        const int nw = j + dw;
                        if ((unsigned)nw > (unsigned)(W - 2)) continue;
                        if (!rowcross && ((unsigned)(lj + dw) <= 31u)) continue;
                        const int n = nh * W + nw;
                        if (pf[n] != n) continue;
                        const int pn = par[n];
                        if (pn == pt || pn == h0 || pn == h1) continue;
                        h1 = h0; h0 = pn;
                        EMIT(pt, pn);
                    }
                }
            }
        }
        __syncthreads();   // protect htab re-init on next iteration
    }
}

// 32x8 px per block; 33x9 label apron via find_ro walks (compression fused here)
__global__ void __launch_bounds__(256)
k_output(const float* __restrict__ ang,
         const int* __restrict__ par, const int* __restrict__ pf,
         const int* __restrict__ c3,
         const int* __restrict__ hp, const int* __restrict__ wp,
         float* __restrict__ out) {
    const int H = hp[0], W = wp[0];
    const int i0 = blockIdx.y << 3;
    const int j0 = blockIdx.x << 5;
    __shared__ int lab[9][33];
    const int tid = threadIdx.x;
    for (int k = tid; k < 9 * 33; k += 256) {
        const int r = k / 33, c = k - r * 33;
        const int gi = min(i0 + r, H - 1), gj = min(j0 + c, W - 1);
        lab[r][c] = find_ro(gi * W + gj, par);   // walk: unions complete at boundary
    }
    __syncthreads();
    const int li2 = tid >> 5, lj2 = tid & 31;
    const int i = i0 + li2, j = j0 + lj2;
    if (i >= H || j >= W) return;
    const int t = i * W + j;
    const float twopi = (float)(2.0 * PI_D);
    const int l = lab[li2][lj2];
    float r0 = 0.0f, r1 = 0.0f;
    bool need = false;
    int l1 = l, l2 = l;
    if (j + 1 < W) { l1 = lab[li2][lj2 + 1]; need |= (l1 != l); }
    if (i + 1 < H) { l2 = lab[li2 + 1][lj2]; need |= (l2 != l); }
    if (need) {
        auto c3v = [&](int x, int xli, int xlj) {   // xli/xlj: 32-tile local coords
            if (xli >= 3 && xli <= 28 && xlj >= 3 && xlj <= 28) return c3[x];
            int p = pf[x];
            p = pf[p];
            return pf[p];
        };
        const float ac = ang[c3v(t, i & 31, j & 31)];
        if (l1 != l) {
            float ad = fabsf(ac - ang[c3v(t + 1, i & 31, (j + 1) & 31)]);
            r0 = fminf(ad, twopi - ad);
        }
        if (l2 != l) {
            float ad = fabsf(ac - ang[c3v(t + W, (i + 1) & 31, j & 31)]);
            r1 = fminf(ad, twopi - ad);
        }
    }
    reinterpret_cast<float2*>(out)[t] = make_float2(r0, r1);
}

extern "C" void kernel_launch(void* const* d_in, const int* in_sizes, int n_in,
                              void* d_out, int out_size, void* d_ws, size_t ws_size,
                              hipStream_t stream) {
    const float* ang = (const float*)d_in[0];
    const int* hp  = (const int*)d_in[1];
    const int* wp  = (const int*)d_in[2];
    const int* tap = (const int*)d_in[3];
    const int N = in_sizes[0];

    int* base = (int*)d_ws;
    if (ws_size < (size_t)3 * (size_t)N * sizeof(int) && N <= 262144) {
        void* p = nullptr;
        hipGetSymbolAddress(&p, HIP_SYMBOL(g_fb));   // host-side query; capture-safe
        base = (int*)p;
    }
    int* pf  = base;
    int* par = base + N;
    int* c3  = base + 2 * N;

    // Grid shapes assume 512x512 (harness-fixed); kernels bounds-check vs hp/wp.
    k_local<<<256, 1024, 0, stream>>>(ang, hp, wp, tap, N, pf, par, c3);
    k_edges<<<256, 320, 0, stream>>>(pf, hp, wp, N, par);
    {
        const int H = 512, W = 512;
        dim3 gridO((W + 31) / 32, (H + 7) / 8);
        k_output<<<gridO, 256, 0, stream>>>(ang, par, pf, c3, hp, wp, (float*)d_out);
    }
}